// Round 1
// baseline (67.911 us; speedup 1.0000x reference)
//
#include <hip/hip_runtime.h>

#define F 512
#define T 512
#define DEPTH 6
#define NL 64
#define BATCH 1024
#define NCOL 3072  // T*DEPTH

typedef __attribute__((ext_vector_type(8))) short short8v;
typedef __attribute__((ext_vector_type(4))) float float4v;

static __device__ __forceinline__ unsigned short f2bf(float f){
  unsigned u = __builtin_bit_cast(unsigned, f);
  unsigned r = (u + 0x7fffu + ((u >> 16) & 1u)) >> 16;  // RNE, finite values
  return (unsigned short)r;
}

// ---------------- kernel 1: x (f32) -> xb (bf16) ----------------
__global__ __launch_bounds__(256) void k_cvt_x(const float* __restrict__ x,
                                               unsigned short* __restrict__ xb){
  int i = blockIdx.x * 256 + threadIdx.x;      // one float4 per thread
  float4 v = ((const float4*)x)[i];
  ushort4 o;
  o.x = f2bf(v.x); o.y = f2bf(v.y); o.z = f2bf(v.z); o.w = f2bf(v.w);
  ((ushort4*)xb)[i] = o;
}

// ------- kernel 2: softmax over F (axis 0) + transpose -> cwT[n][k] bf16 -------
__global__ __launch_bounds__(256) void k_softmax_T(const float* __restrict__ fa,
                                                   unsigned short* __restrict__ cwT){
  __shared__ float red[4][64];
  __shared__ float stat[2][64];     // [0]=max, [1]=1/sum
  __shared__ float tile[64 * 65];   // [n][k] chunk, pad 65 -> conflict-free
  int t = threadIdx.x;
  int c = t & 63, q = t >> 6;
  int n0 = blockIdx.x * 64;
  const float* colp = fa + n0 + c;

  float m = -1e30f;
  for (int i = 0; i < 128; ++i) m = fmaxf(m, colp[(q * 128 + i) * NCOL]);
  red[q][c] = m;
  __syncthreads();
  if (q == 0) stat[0][c] = fmaxf(fmaxf(red[0][c], red[1][c]), fmaxf(red[2][c], red[3][c]));
  __syncthreads();
  float mx = stat[0][c];
  float s = 0.f;
  for (int i = 0; i < 128; ++i) s += __expf(colp[(q * 128 + i) * NCOL] - mx);
  red[q][c] = s;
  __syncthreads();
  if (q == 0) stat[1][c] = 1.0f / (red[0][c] + red[1][c] + red[2][c] + red[3][c]);
  __syncthreads();
  float inv = stat[1][c];

  for (int kc = 0; kc < 8; ++kc){
    int k0 = kc * 64;
    __syncthreads();
    #pragma unroll
    for (int j = 0; j < 16; ++j){
      int kk = q + 4 * j;                       // e = t + 256j -> kk=(t>>6)+4j, nn = t&63 = c
      float v = fa[(k0 + kk) * NCOL + n0 + c];
      tile[c * 65 + kk] = __expf(v - mx) * inv;
    }
    __syncthreads();
    #pragma unroll
    for (int j = 0; j < 2; ++j){
      int s2 = t + 256 * j;
      int nn = s2 >> 3, ko = s2 & 7;
      const float* tp = tile + nn * 65 + ko * 8;
      unsigned short tmp[8];
      #pragma unroll
      for (int z = 0; z < 8; ++z) tmp[z] = f2bf(tp[z]);
      *(int4*)(cwT + (n0 + nn) * F + k0 + ko * 8) = *(const int4*)tmp;
    }
  }
}

// ------- kernel 3: fused MFMA GEMM (fv = xb @ cwT^T) + tree + response -------
// block: 256 thr (4 waves). Tile: 32 b x 16 t (96 n-cols). Grid (32, 32).
#define SMEM3 (18432 + 12544)
__global__ __launch_bounds__(256) void k_main(
    const unsigned short* __restrict__ xb, const unsigned short* __restrict__ cwT,
    const float* __restrict__ thr, const float* __restrict__ ltm,
    const float* __restrict__ resp, float* __restrict__ out){
  __shared__ char smem[SMEM3];
  unsigned short* Al = (unsigned short*)smem;            // [32][72] bf16
  unsigned short* Bl = (unsigned short*)(smem + 4608);   // [96][72] bf16
  float* fvl = (float*)smem;                             // [32][100] f32 (overlays A/B)
  float* rsp = (float*)(smem + 18432);                   // [16][196] f32

  int t = threadIdx.x;
  int b0 = blockIdx.x * 32;
  int t0 = blockIdx.y * 16;
  int n0 = t0 * 6;

  // stage response [16][192] -> LDS (stride 196 to break bank conflicts)
  {
    const float4* rg = (const float4*)(resp + t0 * (NL * 3));
    #pragma unroll
    for (int j = 0; j < 3; ++j){
      int s = t + 256 * j;             // 768 float4 slots
      int tr = s / 48, cf = s % 48;
      *(float4*)(rsp + tr * 196 + cf * 4) = rg[s];
    }
  }

  float4v acc0 = {0.f,0.f,0.f,0.f}, acc1 = {0.f,0.f,0.f,0.f}, acc2 = {0.f,0.f,0.f,0.f};
  int w = t >> 6, l = t & 63;
  int wm = w >> 1, wn3 = (w & 1) * 3;     // wave -> m-half, n-triple
  int lr = l & 15, lg = l >> 4;
  int arow = t >> 3, aseg = t & 7;

  for (int kc = 0; kc < F; kc += 64){
    __syncthreads();
    // stage A: 32 rows x 64 k
    *(int4*)((char*)Al + arow * 144 + aseg * 16) =
        *(const int4*)(xb + (b0 + arow) * F + kc + aseg * 8);
    // stage B: 96 rows x 64 k
    #pragma unroll
    for (int j = 0; j < 3; ++j){
      int s = t + 256 * j;
      int row = s >> 3, seg = s & 7;
      *(int4*)((char*)Bl + row * 144 + seg * 16) =
          *(const int4*)(cwT + (n0 + row) * F + kc + seg * 8);
    }
    __syncthreads();
    #pragma unroll
    for (int ks = 0; ks < 2; ++ks){
      int koff = (ks * 32 + lg * 8) * 2;  // byte offset in a row
      short8v a = *(const short8v*)((char*)Al + (wm * 16 + lr) * 144 + koff);
      short8v bv0 = *(const short8v*)((char*)Bl + ((wn3 + 0) * 16 + lr) * 144 + koff);
      acc0 = __builtin_amdgcn_mfma_f32_16x16x32_bf16(a, bv0, acc0, 0, 0, 0);
      short8v bv1 = *(const short8v*)((char*)Bl + ((wn3 + 1) * 16 + lr) * 144 + koff);
      acc1 = __builtin_amdgcn_mfma_f32_16x16x32_bf16(a, bv1, acc1, 0, 0, 0);
      short8v bv2 = *(const short8v*)((char*)Bl + ((wn3 + 2) * 16 + lr) * 144 + koff);
      acc2 = __builtin_amdgcn_mfma_f32_16x16x32_bf16(a, bv2, acc2, 0, 0, 0);
    }
  }
  __syncthreads();
  // spill fv tile to LDS using verified C/D layout: col=lane&15, row=(lane>>4)*4+reg
  #pragma unroll
  for (int r = 0; r < 4; ++r){
    int m = wm * 16 + lg * 4 + r;
    fvl[m * 100 + (wn3 + 0) * 16 + lr] = acc0[r];
    fvl[m * 100 + (wn3 + 1) * 16 + lr] = acc1[r];
    fvl[m * 100 + (wn3 + 2) * 16 + lr] = acc2[r];
  }
  __syncthreads();

  // tree phase: 512 (b,t) pairs per block, 2 per thread
  #pragma unroll
  for (int p = 0; p < 2; ++p){
    int pair = t + 256 * p;
    int bl = pair >> 4, tl = pair & 15;
    float bins[DEPTH];
    #pragma unroll
    for (int d = 0; d < DEPTH; ++d){
      float v  = fvl[bl * 100 + tl * 6 + d];
      float th = thr[(t0 + tl) * 6 + d];
      float L  = ltm[(t0 + tl) * 6 + d];
      bins[d] = fminf(fmaxf(0.5f * ((v - th) * __expf(-L)) + 0.5f, 0.0f), 1.0f);
    }
    // leaf weights by doubling: bit j of leaf -> (bit ? 1-bins[j] : bins[j])
    float wv[NL];
    wv[0] = bins[0];
    wv[1] = 1.0f - bins[0];
    #pragma unroll
    for (int j = 1; j < DEPTH; ++j){
      int half = 1 << j;
      #pragma unroll
      for (int i = 0; i < half; ++i){
        float o = wv[i];
        wv[i] = o * bins[j];
        wv[i + half] = o * (1.0f - bins[j]);
      }
    }
    float o0 = 0.f, o1 = 0.f, o2 = 0.f;
    const float* rp = rsp + tl * 196;
    #pragma unroll
    for (int no = 0; no < NL; ++no){
      float wn = wv[no];
      o0 += wn * rp[no * 3 + 0];
      o1 += wn * rp[no * 3 + 1];
      o2 += wn * rp[no * 3 + 2];
    }
    float* op = out + (b0 + bl) * (T * 3) + (t0 + tl) * 3;
    op[0] = o0; op[1] = o1; op[2] = o2;
  }
}

extern "C" void kernel_launch(void* const* d_in, const int* in_sizes, int n_in,
                              void* d_out, int out_size, void* d_ws, size_t ws_size,
                              hipStream_t stream){
  const float* x    = (const float*)d_in[0];
  const float* fa   = (const float*)d_in[1];
  const float* thr  = (const float*)d_in[2];
  const float* ltm  = (const float*)d_in[3];
  const float* resp = (const float*)d_in[4];
  float* out = (float*)d_out;

  unsigned short* xb  = (unsigned short*)d_ws;                     // 1 MB
  unsigned short* cwT = (unsigned short*)((char*)d_ws + (1 << 20)); // 3 MB

  k_cvt_x<<<512, 256, 0, stream>>>(x, xb);
  k_softmax_T<<<48, 256, 0, stream>>>(fa, cwT);
  k_main<<<dim3(32, 32), 256, 0, stream>>>(xb, cwT, thr, ltm, resp, out);
}

// Round 2
// 40.789 us; speedup vs baseline: 1.6649x; 1.6649x over previous
//
#include <hip/hip_runtime.h>

#define F 512
#define T 512
#define DEPTH 6
#define NL 64
#define BATCH 1024
#define NCOL 3072  // T*DEPTH

typedef __attribute__((ext_vector_type(8))) short short8v;
typedef __attribute__((ext_vector_type(4))) float float4v;

static __device__ __forceinline__ unsigned short f2bf(float f){
  unsigned u = __builtin_bit_cast(unsigned, f);
  unsigned r = (u + 0x7fffu + ((u >> 16) & 1u)) >> 16;  // RNE, finite values
  return (unsigned short)r;
}

// ---------------- kernel 1: x (f32) -> xb (bf16) ----------------
__global__ __launch_bounds__(256) void k_cvt_x(const float* __restrict__ x,
                                               unsigned short* __restrict__ xb){
  int i = blockIdx.x * 256 + threadIdx.x;      // one float4 per thread
  float4 v = ((const float4*)x)[i];
  ushort4 o;
  o.x = f2bf(v.x); o.y = f2bf(v.y); o.z = f2bf(v.z); o.w = f2bf(v.w);
  ((ushort4*)xb)[i] = o;
}

// ------- kernel 2a: column partial sums of exp(fa) (no max needed: fa in [0,1)) -------
// grid (48, 16): 64 cols x 32 rows per block. partial[16][3072]
__global__ __launch_bounds__(256) void k_colsum(const float* __restrict__ fa,
                                                float* __restrict__ partial){
  __shared__ float red[4][64];
  int t = threadIdx.x;
  int c = t & 63, q = t >> 6;
  int cg = blockIdx.x, rs = blockIdx.y;
  const float* p = fa + (rs * 32 + q * 8) * NCOL + cg * 64 + c;
  float s = 0.f;
  #pragma unroll
  for (int i = 0; i < 8; ++i) s += __expf(p[i * NCOL]);
  red[q][c] = s;
  __syncthreads();
  if (t < 64)
    partial[rs * NCOL + cg * 64 + t] = red[0][t] + red[1][t] + red[2][t] + red[3][t];
}

// ------- kernel 2b: normalize + transpose -> cwT[n][k] bf16 -------
// grid (48, 8): 64 cols (n) x 64 rows (k) per block
__global__ __launch_bounds__(256) void k_norm_T(const float* __restrict__ fa,
                                                const float* __restrict__ partial,
                                                unsigned short* __restrict__ cwT){
  __shared__ float inv[64];
  __shared__ float tile[64 * 65];
  int t = threadIdx.x;
  int c = t & 63, q = t >> 6;
  int n0 = blockIdx.x * 64;
  int k0 = blockIdx.y * 64;
  if (t < 64){
    float s = 0.f;
    #pragma unroll
    for (int i = 0; i < 16; ++i) s += partial[i * NCOL + n0 + t];
    inv[t] = 1.0f / s;
  }
  __syncthreads();
  float iv = inv[c];
  #pragma unroll
  for (int i = 0; i < 16; ++i){
    int kk = q * 16 + i;
    float v = fa[(k0 + kk) * NCOL + n0 + c];
    tile[c * 65 + kk] = __expf(v) * iv;
  }
  __syncthreads();
  #pragma unroll
  for (int j = 0; j < 2; ++j){
    int s2 = t + 256 * j;
    int nn = s2 >> 3, ko = s2 & 7;
    const float* tp = tile + nn * 65 + ko * 8;
    unsigned short tmp[8];
    #pragma unroll
    for (int z = 0; z < 8; ++z) tmp[z] = f2bf(tp[z]);
    *(int4*)(cwT + (n0 + nn) * F + k0 + ko * 8) = *(const int4*)tmp;
  }
}

// ------- kernel 3: fused MFMA GEMM (fv = xb @ cwT^T) + tree + response -------
// block: 256 thr (4 waves). Tile: 32 b x 16 t (96 n-cols). Grid (32, 32).
#define SMEM3 (18432 + 12544)
__global__ __launch_bounds__(256) void k_main(
    const unsigned short* __restrict__ xb, const unsigned short* __restrict__ cwT,
    const float* __restrict__ thr, const float* __restrict__ ltm,
    const float* __restrict__ resp, float* __restrict__ out){
  __shared__ char smem[SMEM3];
  unsigned short* Al = (unsigned short*)smem;            // [32][72] bf16
  unsigned short* Bl = (unsigned short*)(smem + 4608);   // [96][72] bf16
  float* fvl = (float*)smem;                             // [32][100] f32 (overlays A/B)
  float* rsp = (float*)(smem + 18432);                   // [16][196] f32

  int t = threadIdx.x;
  int b0 = blockIdx.x * 32;
  int t0 = blockIdx.y * 16;
  int n0 = t0 * 6;

  // stage response [16][192] -> LDS (stride 196 to break bank conflicts)
  {
    const float4* rg = (const float4*)(resp + t0 * (NL * 3));
    #pragma unroll
    for (int j = 0; j < 3; ++j){
      int s = t + 256 * j;             // 768 float4 slots
      int tr = s / 48, cf = s % 48;
      *(float4*)(rsp + tr * 196 + cf * 4) = rg[s];
    }
  }

  float4v acc0 = {0.f,0.f,0.f,0.f}, acc1 = {0.f,0.f,0.f,0.f}, acc2 = {0.f,0.f,0.f,0.f};
  int w = t >> 6, l = t & 63;
  int wm = w >> 1, wn3 = (w & 1) * 3;     // wave -> m-half, n-triple
  int lr = l & 15, lg = l >> 4;
  int arow = t >> 3, aseg = t & 7;

  for (int kc = 0; kc < F; kc += 64){
    __syncthreads();
    // stage A: 32 rows x 64 k
    *(int4*)((char*)Al + arow * 144 + aseg * 16) =
        *(const int4*)(xb + (b0 + arow) * F + kc + aseg * 8);
    // stage B: 96 rows x 64 k
    #pragma unroll
    for (int j = 0; j < 3; ++j){
      int s = t + 256 * j;
      int row = s >> 3, seg = s & 7;
      *(int4*)((char*)Bl + row * 144 + seg * 16) =
          *(const int4*)(cwT + (n0 + row) * F + kc + seg * 8);
    }
    __syncthreads();
    #pragma unroll
    for (int ks = 0; ks < 2; ++ks){
      int koff = (ks * 32 + lg * 8) * 2;  // byte offset in a row
      short8v a = *(const short8v*)((char*)Al + (wm * 16 + lr) * 144 + koff);
      short8v bv0 = *(const short8v*)((char*)Bl + ((wn3 + 0) * 16 + lr) * 144 + koff);
      acc0 = __builtin_amdgcn_mfma_f32_16x16x32_bf16(a, bv0, acc0, 0, 0, 0);
      short8v bv1 = *(const short8v*)((char*)Bl + ((wn3 + 1) * 16 + lr) * 144 + koff);
      acc1 = __builtin_amdgcn_mfma_f32_16x16x32_bf16(a, bv1, acc1, 0, 0, 0);
      short8v bv2 = *(const short8v*)((char*)Bl + ((wn3 + 2) * 16 + lr) * 144 + koff);
      acc2 = __builtin_amdgcn_mfma_f32_16x16x32_bf16(a, bv2, acc2, 0, 0, 0);
    }
  }
  __syncthreads();
  // spill fv tile to LDS using verified C/D layout: col=lane&15, row=(lane>>4)*4+reg
  #pragma unroll
  for (int r = 0; r < 4; ++r){
    int m = wm * 16 + lg * 4 + r;
    fvl[m * 100 + (wn3 + 0) * 16 + lr] = acc0[r];
    fvl[m * 100 + (wn3 + 1) * 16 + lr] = acc1[r];
    fvl[m * 100 + (wn3 + 2) * 16 + lr] = acc2[r];
  }
  __syncthreads();

  // tree phase: 512 (b,t) pairs per block, 2 per thread
  #pragma unroll
  for (int p = 0; p < 2; ++p){
    int pair = t + 256 * p;
    int bl = pair >> 4, tl = pair & 15;
    float bins[DEPTH];
    #pragma unroll
    for (int d = 0; d < DEPTH; ++d){
      float v  = fvl[bl * 100 + tl * 6 + d];
      float th = thr[(t0 + tl) * 6 + d];
      float L  = ltm[(t0 + tl) * 6 + d];
      bins[d] = fminf(fmaxf(0.5f * ((v - th) * __expf(-L)) + 0.5f, 0.0f), 1.0f);
    }
    // leaf weights by doubling: bit j of leaf -> (bit ? 1-bins[j] : bins[j])
    float wv[NL];
    wv[0] = bins[0];
    wv[1] = 1.0f - bins[0];
    #pragma unroll
    for (int j = 1; j < DEPTH; ++j){
      int half = 1 << j;
      #pragma unroll
      for (int i = 0; i < half; ++i){
        float o = wv[i];
        wv[i] = o * bins[j];
        wv[i + half] = o * (1.0f - bins[j]);
      }
    }
    float o0 = 0.f, o1 = 0.f, o2 = 0.f;
    const float* rp = rsp + tl * 196;
    #pragma unroll
    for (int no = 0; no < NL; ++no){
      float wn = wv[no];
      o0 += wn * rp[no * 3 + 0];
      o1 += wn * rp[no * 3 + 1];
      o2 += wn * rp[no * 3 + 2];
    }
    float* op = out + (b0 + bl) * (T * 3) + (t0 + tl) * 3;
    op[0] = o0; op[1] = o1; op[2] = o2;
  }
}

extern "C" void kernel_launch(void* const* d_in, const int* in_sizes, int n_in,
                              void* d_out, int out_size, void* d_ws, size_t ws_size,
                              hipStream_t stream){
  const float* x    = (const float*)d_in[0];
  const float* fa   = (const float*)d_in[1];
  const float* thr  = (const float*)d_in[2];
  const float* ltm  = (const float*)d_in[3];
  const float* resp = (const float*)d_in[4];
  float* out = (float*)d_out;

  unsigned short* xb  = (unsigned short*)d_ws;                      // @0, 1 MB
  unsigned short* cwT = (unsigned short*)((char*)d_ws + (1 << 20)); // @1MB, 3 MB
  float* partial      = (float*)((char*)d_ws + (4 << 20));          // @4MB, 192 KB

  k_cvt_x<<<512, 256, 0, stream>>>(x, xb);
  k_colsum<<<dim3(48, 16), 256, 0, stream>>>(fa, partial);
  k_norm_T<<<dim3(48, 8), 256, 0, stream>>>(fa, partial, cwT);
  k_main<<<dim3(32, 32), 256, 0, stream>>>(xb, cwT, thr, ltm, resp, out);
}

// Round 3
// 35.594 us; speedup vs baseline: 1.9079x; 1.1460x over previous
//
#include <hip/hip_runtime.h>

#define F 512
#define T 512
#define DEPTH 6
#define NL 64
#define NCOL 3072  // T*DEPTH

typedef __attribute__((ext_vector_type(8))) short short8v;
typedef __attribute__((ext_vector_type(4))) float float4v;

static __device__ __forceinline__ unsigned short f2bf(float f){
  unsigned u = __builtin_bit_cast(unsigned, f);
  unsigned r = (u + 0x7fffu + ((u >> 16) & 1u)) >> 16;  // RNE, finite values
  return (unsigned short)r;
}

// ------- kernel 1: column partial sums of exp(fa) (no max pass: fa in [0,1)) -------
// grid (48, 16): 64 cols x 32 rows per block. partial[16][3072]
__global__ __launch_bounds__(256) void k_colsum(const float* __restrict__ fa,
                                                float* __restrict__ partial){
  __shared__ float red[4][64];
  int t = threadIdx.x;
  int c = t & 63, q = t >> 6;
  int cg = blockIdx.x, rs = blockIdx.y;
  const float* p = fa + (rs * 32 + q * 8) * NCOL + cg * 64 + c;
  float s = 0.f;
  #pragma unroll
  for (int i = 0; i < 8; ++i) s += __expf(p[i * NCOL]);
  red[q][c] = s;
  __syncthreads();
  if (t < 64)
    partial[rs * NCOL + cg * 64 + t] = red[0][t] + red[1][t] + red[2][t] + red[3][t];
}

// ------- kernel 2: normalize + transpose -> cwT[n][k] bf16 -------
// grid (48, 8): 64 cols (n) x 64 rows (k) per block
__global__ __launch_bounds__(256) void k_norm_T(const float* __restrict__ fa,
                                                const float* __restrict__ partial,
                                                unsigned short* __restrict__ cwT){
  __shared__ float inv[64];
  __shared__ float tile[64 * 65];
  int t = threadIdx.x;
  int c = t & 63, q = t >> 6;
  int n0 = blockIdx.x * 64;
  int k0 = blockIdx.y * 64;
  if (t < 64){
    float s = 0.f;
    #pragma unroll
    for (int i = 0; i < 16; ++i) s += partial[i * NCOL + n0 + t];
    inv[t] = 1.0f / s;
  }
  __syncthreads();
  float iv = inv[c];
  #pragma unroll
  for (int i = 0; i < 16; ++i){
    int kk = q * 16 + i;
    float v = fa[(k0 + kk) * NCOL + n0 + c];
    tile[c * 65 + kk] = __expf(v) * iv;
  }
  __syncthreads();
  #pragma unroll
  for (int j = 0; j < 2; ++j){
    int s2 = t + 256 * j;
    int nn = s2 >> 3, ko = s2 & 7;
    const float* tp = tile + nn * 65 + ko * 8;
    unsigned short tmp[8];
    #pragma unroll
    for (int z = 0; z < 8; ++z) tmp[z] = f2bf(tp[z]);
    *(int4*)(cwT + (n0 + nn) * F + k0 + ko * 8) = *(const int4*)tmp;
  }
}

// ------- kernel 3: fused cvt + MFMA GEMM (fv = x @ cwT^T) + tree + response -------
// block: 256 thr (4 waves). Tile: 32 b x 16 t (96 n-cols). Grid (32, 32).
#define RSP_STRIDE 260              // 64 leaves * 4 + 4 pad -> 2-way banks across tl
#define SMEM3 (18432 + 16640)
__global__ __launch_bounds__(256) void k_main(
    const float* __restrict__ x, const unsigned short* __restrict__ cwT,
    const float* __restrict__ thr, const float* __restrict__ ltm,
    const float* __restrict__ resp, float* __restrict__ out){
  __shared__ char smem[SMEM3];
  unsigned short* Al = (unsigned short*)smem;            // [32][72] bf16
  unsigned short* Bl = (unsigned short*)(smem + 4608);   // [96][72] bf16
  float* fvl = (float*)smem;                             // [32][100] f32 (overlays A/B)
  float* rsp = (float*)(smem + 18432);                   // [16][RSP_STRIDE] f32

  int t = threadIdx.x;
  int b0 = blockIdx.x * 32;
  int t0 = blockIdx.y * 16;
  int n0 = t0 * 6;

  // stage response: [16 trees][leaf*4+c] padded float4 slots
  {
    const float4* rg = (const float4*)(resp + t0 * (NL * 3));
    #pragma unroll
    for (int j = 0; j < 3; ++j){
      int s = t + 256 * j;             // 768 float4 slots
      int tr = s / 48, m0 = (s % 48) * 4;
      float4 v = rg[s];
      float vv[4] = {v.x, v.y, v.z, v.w};
      #pragma unroll
      for (int z = 0; z < 4; ++z){
        int m = m0 + z;
        rsp[tr * RSP_STRIDE + (m / 3) * 4 + (m % 3)] = vv[z];
      }
    }
  }

  float4v acc0 = {0.f,0.f,0.f,0.f}, acc1 = {0.f,0.f,0.f,0.f}, acc2 = {0.f,0.f,0.f,0.f};
  int w = t >> 6, l = t & 63;
  int wm = w >> 1, wn3 = (w & 1) * 3;     // wave -> m-half, n-triple
  int lr = l & 15, lg = l >> 4;
  int arow = t >> 3, aseg = t & 7;

  for (int kc = 0; kc < F; kc += 64){
    __syncthreads();
    // stage A: 32 rows x 64 k, f32 -> bf16 inline
    {
      const float* xp = x + (b0 + arow) * F + kc + aseg * 8;
      float4 xa = *(const float4*)xp;
      float4 xc = *(const float4*)(xp + 4);
      unsigned short tmp[8];
      tmp[0] = f2bf(xa.x); tmp[1] = f2bf(xa.y); tmp[2] = f2bf(xa.z); tmp[3] = f2bf(xa.w);
      tmp[4] = f2bf(xc.x); tmp[5] = f2bf(xc.y); tmp[6] = f2bf(xc.z); tmp[7] = f2bf(xc.w);
      *(int4*)((char*)Al + arow * 144 + aseg * 16) = *(const int4*)tmp;
    }
    // stage B: 96 rows x 64 k
    #pragma unroll
    for (int j = 0; j < 3; ++j){
      int s = t + 256 * j;
      int row = s >> 3, seg = s & 7;
      *(int4*)((char*)Bl + row * 144 + seg * 16) =
          *(const int4*)(cwT + (n0 + row) * F + kc + seg * 8);
    }
    __syncthreads();
    #pragma unroll
    for (int ks = 0; ks < 2; ++ks){
      int koff = (ks * 32 + lg * 8) * 2;  // byte offset in a row
      short8v a = *(const short8v*)((char*)Al + (wm * 16 + lr) * 144 + koff);
      short8v bv0 = *(const short8v*)((char*)Bl + ((wn3 + 0) * 16 + lr) * 144 + koff);
      acc0 = __builtin_amdgcn_mfma_f32_16x16x32_bf16(a, bv0, acc0, 0, 0, 0);
      short8v bv1 = *(const short8v*)((char*)Bl + ((wn3 + 1) * 16 + lr) * 144 + koff);
      acc1 = __builtin_amdgcn_mfma_f32_16x16x32_bf16(a, bv1, acc1, 0, 0, 0);
      short8v bv2 = *(const short8v*)((char*)Bl + ((wn3 + 2) * 16 + lr) * 144 + koff);
      acc2 = __builtin_amdgcn_mfma_f32_16x16x32_bf16(a, bv2, acc2, 0, 0, 0);
    }
  }
  __syncthreads();
  // spill fv tile to LDS using verified C/D layout: col=lane&15, row=(lane>>4)*4+reg
  #pragma unroll
  for (int r = 0; r < 4; ++r){
    int m = wm * 16 + lg * 4 + r;
    fvl[m * 100 + (wn3 + 0) * 16 + lr] = acc0[r];
    fvl[m * 100 + (wn3 + 1) * 16 + lr] = acc1[r];
    fvl[m * 100 + (wn3 + 2) * 16 + lr] = acc2[r];
  }
  __syncthreads();

  // ---- tree phase: thread owns tree tl for rows bl0 and bl0+16 ----
  int tl = t & 15, bl0 = t >> 4;
  const float* thp = thr + (t0 + tl) * 6;
  const float* ltp = ltm + (t0 + tl) * 6;
  float bA[DEPTH], bB[DEPTH];
  #pragma unroll
  for (int d = 0; d < DEPTH; ++d){
    float a = 0.5f * __expf(-ltp[d]);
    float c = 0.5f - thp[d] * a;
    float fA = fvl[bl0 * 100 + tl * 6 + d];
    float fB = fvl[(bl0 + 16) * 100 + tl * 6 + d];
    bA[d] = fminf(fmaxf(fA * a + c, 0.0f), 1.0f);
    bB[d] = fminf(fmaxf(fB * a + c, 0.0f), 1.0f);
  }
  // leaf weights for bits 0..3 (16 per pair) by doubling
  float wA[16], wB[16];
  wA[0] = bA[0]; wA[1] = 1.0f - bA[0];
  wB[0] = bB[0]; wB[1] = 1.0f - bB[0];
  #pragma unroll
  for (int j = 1; j < 4; ++j){
    int half = 1 << j;
    float gA = bA[j], gB = bB[j];
    #pragma unroll
    for (int i = 0; i < half; ++i){
      float oA = wA[i], oB = wB[i];
      wA[i] = oA * gA; wA[i + half] = oA - wA[i];       // oA*(1-gA)
      wB[i] = oB * gB; wB[i + half] = oB - wB[i];
    }
  }
  float p4A = bA[4], p5A = bA[5], p4B = bB[4], p5B = bB[5];
  float aA0 = 0.f, aA1 = 0.f, aA2 = 0.f, aB0 = 0.f, aB1 = 0.f, aB2 = 0.f;
  const float* rp = rsp + tl * RSP_STRIDE;
  #pragma unroll
  for (int i = 0; i < 16; ++i){
    float4 r0  = *(const float4*)(rp + i * 4);
    float4 r16 = *(const float4*)(rp + (i + 16) * 4);
    float4 r32 = *(const float4*)(rp + (i + 32) * 4);
    float4 r48 = *(const float4*)(rp + (i + 48) * 4);
    float wiA = wA[i], wiB = wB[i];
    #define COMP(c, accA, accB)                                     \
    {                                                               \
      float d0 = r0.c - r32.c, d1 = r16.c - r48.c;                  \
      float m0 = r32.c + p5A * d0, m1 = r48.c + p5A * d1;           \
      accA += wiA * (m1 + p4A * (m0 - m1));                         \
      float n0v = r32.c + p5B * d0, n1v = r48.c + p5B * d1;         \
      accB += wiB * (n1v + p4B * (n0v - n1v));                      \
    }
    COMP(x, aA0, aB0)
    COMP(y, aA1, aB1)
    COMP(z, aA2, aB2)
    #undef COMP
  }
  float* opA = out + (b0 + bl0) * (T * 3) + (t0 + tl) * 3;
  opA[0] = aA0; opA[1] = aA1; opA[2] = aA2;
  float* opB = out + (b0 + bl0 + 16) * (T * 3) + (t0 + tl) * 3;
  opB[0] = aB0; opB[1] = aB1; opB[2] = aB2;
}

extern "C" void kernel_launch(void* const* d_in, const int* in_sizes, int n_in,
                              void* d_out, int out_size, void* d_ws, size_t ws_size,
                              hipStream_t stream){
  const float* x    = (const float*)d_in[0];
  const float* fa   = (const float*)d_in[1];
  const float* thr  = (const float*)d_in[2];
  const float* ltm  = (const float*)d_in[3];
  const float* resp = (const float*)d_in[4];
  float* out = (float*)d_out;

  unsigned short* cwT = (unsigned short*)d_ws;              // @0, 3 MB
  float* partial      = (float*)((char*)d_ws + (4 << 20));  // @4MB, 192 KB

  k_colsum<<<dim3(48, 16), 256, 0, stream>>>(fa, partial);
  k_norm_T<<<dim3(48, 8), 256, 0, stream>>>(fa, partial, cwT);
  k_main<<<dim3(32, 32), 256, 0, stream>>>(x, cwT, thr, ltm, resp, out);
}

// Round 4
// 34.107 us; speedup vs baseline: 1.9911x; 1.0436x over previous
//
#include <hip/hip_runtime.h>

#define F 512
#define T 512
#define DEPTH 6
#define NL 64
#define NCOL 3072  // T*DEPTH

typedef __attribute__((ext_vector_type(8))) short short8v;
typedef __attribute__((ext_vector_type(4))) float float4v;

static __device__ __forceinline__ unsigned short f2bf(float f){
  unsigned u = __builtin_bit_cast(unsigned, f);
  unsigned r = (u + 0x7fffu + ((u >> 16) & 1u)) >> 16;  // RNE, finite values
  return (unsigned short)r;
}

// ------- kernel 1: column partial sums of exp(fa) + fused x->bf16 convert -------
// grid (48, 16): 64 cols x 32 rows per block. partial[16][3072]
__global__ __launch_bounds__(256) void k_colsum(const float* __restrict__ fa,
                                                float* __restrict__ partial,
                                                const float* __restrict__ x,
                                                unsigned short* __restrict__ xb){
  __shared__ float red[4][64];
  int t = threadIdx.x;
  int c = t & 63, q = t >> 6;
  int cg = blockIdx.x, rs = blockIdx.y;
  // fused: convert x (524288 f32) to bf16, 1 float4 per thread over 512 blocks
  int bid = blockIdx.y * 48 + blockIdx.x;
  if (bid < 512){
    int i = bid * 256 + t;
    float4 v = ((const float4*)x)[i];
    ushort4 o;
    o.x = f2bf(v.x); o.y = f2bf(v.y); o.z = f2bf(v.z); o.w = f2bf(v.w);
    ((ushort4*)xb)[i] = o;
  }
  const float* p = fa + (rs * 32 + q * 8) * NCOL + cg * 64 + c;
  float s = 0.f;
  #pragma unroll
  for (int i = 0; i < 8; ++i) s += __expf(p[i * NCOL]);
  red[q][c] = s;
  __syncthreads();
  if (t < 64)
    partial[rs * NCOL + cg * 64 + t] = red[0][t] + red[1][t] + red[2][t] + red[3][t];
}

// ------- kernel 2: normalize + transpose -> cwT[n][k] bf16 -------
// grid (48, 8): 64 cols (n) x 64 rows (k) per block
__global__ __launch_bounds__(256) void k_norm_T(const float* __restrict__ fa,
                                                const float* __restrict__ partial,
                                                unsigned short* __restrict__ cwT){
  __shared__ float inv[64];
  __shared__ float tile[64 * 65];
  int t = threadIdx.x;
  int c = t & 63, q = t >> 6;
  int n0 = blockIdx.x * 64;
  int k0 = blockIdx.y * 64;
  if (t < 64){
    float s = 0.f;
    #pragma unroll
    for (int i = 0; i < 16; ++i) s += partial[i * NCOL + n0 + t];
    inv[t] = 1.0f / s;
  }
  __syncthreads();
  float iv = inv[c];
  #pragma unroll
  for (int i = 0; i < 16; ++i){
    int kk = q * 16 + i;
    float v = fa[(k0 + kk) * NCOL + n0 + c];
    tile[c * 65 + kk] = __expf(v) * iv;
  }
  __syncthreads();
  #pragma unroll
  for (int j = 0; j < 2; ++j){
    int s2 = t + 256 * j;
    int nn = s2 >> 3, ko = s2 & 7;
    const float* tp = tile + nn * 65 + ko * 8;
    unsigned short tmp[8];
    #pragma unroll
    for (int z = 0; z < 8; ++z) tmp[z] = f2bf(tp[z]);
    *(int4*)(cwT + (n0 + nn) * F + k0 + ko * 8) = *(const int4*)tmp;
  }
}

// ------- kernel 3: 2-phase pipelined MFMA GEMM + tree + response -------
// Tile 64 b-rows x 16 trees (96 n). 256 thr / 4 waves (2m x 2n). Grid (16, 32).
// LDS: A dbuf 2x[64][72]bf16 @0, B dbuf 2x[96][72]bf16 @18432, rsp @46080.
// fvl [64][100]f32 overlays A/B region after GEMM.
#define RSP_STRIDE 260
#define SMEM3 (46080 + 16640)
__global__ __launch_bounds__(256) void k_main(
    const unsigned short* __restrict__ xb, const unsigned short* __restrict__ cwT,
    const float* __restrict__ thr, const float* __restrict__ ltm,
    const float* __restrict__ resp, float* __restrict__ out){
  __shared__ char smem[SMEM3];
  float* fvl = (float*)smem;                       // [64][100] f32 (post-GEMM overlay)
  float* rsp = (float*)(smem + 46080);             // [16][RSP_STRIDE] f32

  int t = threadIdx.x;
  int b0 = blockIdx.x * 64;
  int t0 = blockIdx.y * 16;
  int n0 = t0 * 6;

  // stage response: [16 trees][leaf*4+c] padded float4 slots
  {
    const float4* rg = (const float4*)(resp + t0 * (NL * 3));
    #pragma unroll
    for (int j = 0; j < 3; ++j){
      int s = t + 256 * j;             // 768 float4 slots
      int tr = s / 48, m0 = (s % 48) * 4;
      float4 v = rg[s];
      float vv[4] = {v.x, v.y, v.z, v.w};
      #pragma unroll
      for (int z = 0; z < 4; ++z){
        int m = m0 + z;
        rsp[tr * RSP_STRIDE + (m / 3) * 4 + (m % 3)] = vv[z];
      }
    }
  }

  // staging decomposition
  int arow = t >> 2, acol = (t & 3) * 16;          // A: 64 rows x 64 k, 32B/thread
  int brow = t >> 3, bseg = t & 7;                 // B: rows brow+32j, 16B/thread each
  const unsigned short* xp  = xb  + (b0 + arow) * F + acol;
  const unsigned short* bp0 = cwT + (n0 + brow) * F + bseg * 8;

  // wave/fragment decomposition (2m x 2n)
  int w = t >> 6, l = t & 63;
  int wm = w >> 1, wn = w & 1;
  int lr = l & 15, lg = l >> 4;
  float4v acc[2][3];
  #pragma unroll
  for (int i = 0; i < 2; ++i)
    #pragma unroll
    for (int j = 0; j < 3; ++j) acc[i][j] = (float4v){0.f,0.f,0.f,0.f};

  // prologue: load chunk 0
  int4 ra0 = *(const int4*)(xp);
  int4 ra1 = *(const int4*)(xp + 8);
  int4 rb0 = *(const int4*)(bp0);
  int4 rb1 = *(const int4*)(bp0 + 32 * F);
  int4 rb2 = *(const int4*)(bp0 + 64 * F);

  #pragma unroll
  for (int c = 0; c < 8; ++c){
    char* Ab = smem + (c & 1) * 9216;
    char* Bb = smem + 18432 + (c & 1) * 13824;
    // write staged regs for chunk c (compiler waits vmcnt on the reg deps)
    *(int4*)(Ab + arow * 144 + (t & 3) * 32)      = ra0;
    *(int4*)(Ab + arow * 144 + (t & 3) * 32 + 16) = ra1;
    *(int4*)(Bb + brow * 144 + bseg * 16)         = rb0;
    *(int4*)(Bb + (brow + 32) * 144 + bseg * 16)  = rb1;
    *(int4*)(Bb + (brow + 64) * 144 + bseg * 16)  = rb2;
    __syncthreads();
    // issue next chunk's loads (fly during this chunk's compute)
    if (c < 7){
      int kc = (c + 1) * 64;
      ra0 = *(const int4*)(xp + kc);
      ra1 = *(const int4*)(xp + kc + 8);
      rb0 = *(const int4*)(bp0 + kc);
      rb1 = *(const int4*)(bp0 + 32 * F + kc);
      rb2 = *(const int4*)(bp0 + 64 * F + kc);
    }
    // compute chunk c
    #pragma unroll
    for (int ks = 0; ks < 2; ++ks){
      int koff = ks * 64 + lg * 16;      // byte offset within 64k row (128B data)
      short8v a0 = *(const short8v*)(Ab + (wm * 32 + lr) * 144 + koff);
      short8v a1 = *(const short8v*)(Ab + (wm * 32 + 16 + lr) * 144 + koff);
      short8v b0 = *(const short8v*)(Bb + (wn * 48 + lr) * 144 + koff);
      short8v b1 = *(const short8v*)(Bb + (wn * 48 + 16 + lr) * 144 + koff);
      short8v b2 = *(const short8v*)(Bb + (wn * 48 + 32 + lr) * 144 + koff);
      acc[0][0] = __builtin_amdgcn_mfma_f32_16x16x32_bf16(a0, b0, acc[0][0], 0, 0, 0);
      acc[0][1] = __builtin_amdgcn_mfma_f32_16x16x32_bf16(a0, b1, acc[0][1], 0, 0, 0);
      acc[0][2] = __builtin_amdgcn_mfma_f32_16x16x32_bf16(a0, b2, acc[0][2], 0, 0, 0);
      acc[1][0] = __builtin_amdgcn_mfma_f32_16x16x32_bf16(a1, b0, acc[1][0], 0, 0, 0);
      acc[1][1] = __builtin_amdgcn_mfma_f32_16x16x32_bf16(a1, b1, acc[1][1], 0, 0, 0);
      acc[1][2] = __builtin_amdgcn_mfma_f32_16x16x32_bf16(a1, b2, acc[1][2], 0, 0, 0);
    }
  }
  __syncthreads();   // all waves done computing before fvl overlays A/B
  // spill fv: C/D layout col=lane&15, row=(lane>>4)*4+reg
  #pragma unroll
  for (int fm = 0; fm < 2; ++fm)
    #pragma unroll
    for (int fn = 0; fn < 3; ++fn)
      #pragma unroll
      for (int r = 0; r < 4; ++r)
        fvl[(wm * 32 + fm * 16 + lg * 4 + r) * 100 + wn * 48 + fn * 16 + lr] = acc[fm][fn][r];
  __syncthreads();

  // ---- tree phase: thread owns tree tl for 4 rows bl0+16p ----
  int tl = t & 15, bl0 = t >> 4;
  const float* thp = thr + (t0 + tl) * 6;
  const float* ltp = ltm + (t0 + tl) * 6;
  float av[DEPTH], cv[DEPTH];
  #pragma unroll
  for (int d = 0; d < DEPTH; ++d){
    av[d] = 0.5f * __expf(-ltp[d]);
    cv[d] = 0.5f - thp[d] * av[d];
  }
  float wv[4][16], p4[4], p5[4];
  #pragma unroll
  for (int p = 0; p < 4; ++p){
    int bl = bl0 + 16 * p;
    float bn[DEPTH];
    #pragma unroll
    for (int d = 0; d < DEPTH; ++d)
      bn[d] = fminf(fmaxf(fvl[bl * 100 + tl * 6 + d] * av[d] + cv[d], 0.0f), 1.0f);
    wv[p][0] = bn[0]; wv[p][1] = 1.0f - bn[0];
    #pragma unroll
    for (int j = 1; j < 4; ++j){
      int half = 1 << j;
      float g = bn[j];
      #pragma unroll
      for (int i = 0; i < half; ++i){
        float o = wv[p][i];
        wv[p][i] = o * g;
        wv[p][i + half] = o - wv[p][i];   // o*(1-g)
      }
    }
    p4[p] = bn[4]; p5[p] = bn[5];
  }
  float oa[4][3];
  #pragma unroll
  for (int p = 0; p < 4; ++p){ oa[p][0] = 0.f; oa[p][1] = 0.f; oa[p][2] = 0.f; }
  const float* rp = rsp + tl * RSP_STRIDE;
  #pragma unroll
  for (int i = 0; i < 16; ++i){
    float4 r0  = *(const float4*)(rp + i * 4);
    float4 r16 = *(const float4*)(rp + (i + 16) * 4);
    float4 r32 = *(const float4*)(rp + (i + 32) * 4);
    float4 r48 = *(const float4*)(rp + (i + 48) * 4);
    #define COMP(cc, ci)                                            \
    {                                                               \
      float d0 = r0.cc - r32.cc, d1 = r16.cc - r48.cc;              \
      _Pragma("unroll")                                             \
      for (int p = 0; p < 4; ++p){                                  \
        float m0 = r32.cc + p5[p] * d0, m1 = r48.cc + p5[p] * d1;   \
        oa[p][ci] += wv[p][i] * (m1 + p4[p] * (m0 - m1));           \
      }                                                             \
    }
    COMP(x, 0)
    COMP(y, 1)
    COMP(z, 2)
    #undef COMP
  }
  #pragma unroll
  for (int p = 0; p < 4; ++p){
    float* op = out + (b0 + bl0 + 16 * p) * (T * 3) + (t0 + tl) * 3;
    op[0] = oa[p][0]; op[1] = oa[p][1]; op[2] = oa[p][2];
  }
}

extern "C" void kernel_launch(void* const* d_in, const int* in_sizes, int n_in,
                              void* d_out, int out_size, void* d_ws, size_t ws_size,
                              hipStream_t stream){
  const float* x    = (const float*)d_in[0];
  const float* fa   = (const float*)d_in[1];
  const float* thr  = (const float*)d_in[2];
  const float* ltm  = (const float*)d_in[3];
  const float* resp = (const float*)d_in[4];
  float* out = (float*)d_out;

  unsigned short* cwT = (unsigned short*)d_ws;                      // @0, 3 MB
  unsigned short* xb  = (unsigned short*)((char*)d_ws + (3 << 20)); // @3MB, 1 MB
  float* partial      = (float*)((char*)d_ws + (4 << 20));          // @4MB, 192 KB

  k_colsum<<<dim3(48, 16), 256, 0, stream>>>(fa, partial, x, xb);
  k_norm_T<<<dim3(48, 8), 256, 0, stream>>>(fa, partial, cwT);
  k_main<<<dim3(16, 32), 256, 0, stream>>>(xb, cwT, thr, ltm, resp, out);
}